// Round 8
// baseline (286.001 us; speedup 1.0000x reference)
//
#include <hip/hip_runtime.h>
#include <math.h>

// Capsule routing B=32, N=1024(j), D=256(k), NC=32(i), DC=64(d). Factored
// (no u_hat), MFMA 16x16x32 bf16:
//   delta[j,i] = U[b,j,:].w[:,i]; e = exp(logit); t[i,k] = sum_j e[i,j] U[j,k]
//   s = tW_i; v = s*rsqrt(||s||^2+eps*sef^2); w = W_i v
// History: R1 traffic (neutral), R2 atomics (-), R3 tail-fusion (--), R4/R5
// coop grid.sync ~60us each (dead), R6 soft barriers (dead), R16 k_pass
// barrier/register restructure (neutral). Surviving model: ~80us thin work +
// ~10us per launch gap x 5. Round-17: cut a launch. k_init+k_sv0 merge into
// ONE kernel k_sv0d: block b (32 blocks) does the j-colsum itself (1MB U),
// then s-phase (wave=capsule, coalesced W columns), squash, and a DIRECT-W
// w-phase (per-thread contiguous 256B row chunks, L2-resident) -> no WT
// dependency -> no circularity. The 128 WT-transpose blocks ride in the same
// launch (WT first needed by sv1, two launches later). 6 -> 5 launches.
// k_pass = R16-proven body, k_sv = R0-proven body (mode-0 path deleted).

typedef short v8s __attribute__((ext_vector_type(8)));
typedef short v4s __attribute__((ext_vector_type(4)));
typedef float v4f __attribute__((ext_vector_type(4)));

__device__ __forceinline__ unsigned short f2bf(float x) {
    unsigned u = __float_as_uint(x);
    u = u + 0x7fffu + ((u >> 16) & 1u);
    return (unsigned short)(u >> 16);
}
__device__ __forceinline__ float bf2f(unsigned short h) {
    return __uint_as_float(((unsigned)h) << 16);
}

// ---------------------------------------------------------------------------
// k_sv0d: blocks 0..31 = batch b: colsum t (uniform softmax iter-0) -> s ->
// v -> w -> wbt hi/lo, all in one block (sef=1). blocks 32..159: W^T tiles.
__global__ __launch_bounds__(1024) void k_sv0d(const float* __restrict__ U,
                                               const float* __restrict__ W,
                                               float* __restrict__ WT,
                                               short* __restrict__ wbt_h,
                                               short* __restrict__ wbt_l) {
    const int bid = blockIdx.x, tid = threadIdx.x;
    if (bid >= 32) {
        // ---- W transpose: 64x64 tile per block, 1024 threads ----
        __shared__ float tile[64 * 65];
        int tix = bid - 32;                      // 0..127
        int k0 = (tix >> 5) << 6, c0 = (tix & 31) << 6;
        int cc = tid & 63, rg = tid >> 6;        // 16 groups of 4 rows
        #pragma unroll
        for (int e = 0; e < 4; ++e) {
            int kk = (rg << 2) + e;
            tile[kk * 65 + cc] = W[(k0 + kk) * 2048 + c0 + cc];
        }
        __syncthreads();
        int kk = tid & 63;
        #pragma unroll
        for (int e = 0; e < 4; ++e) {
            int c = (rg << 2) + e;
            WT[(c0 + c) * 256 + k0 + kk] = tile[kk * 65 + c];
        }
        return;
    }
    // ---- batch block b = bid ----
    __shared__ float part[4 * 256];
    __shared__ float t_lds[256];
    __shared__ float v_all[32 * 64];
    const int b = bid;

    // colsum: k = tid&255, jg = tid>>8 (4 groups of 256 j)
    {
        int k = tid & 255, jg = tid >> 8;
        const float* Up = U + (b << 18) + (jg << 16) + k;
        float acc = 0.f;
        #pragma unroll 8
        for (int jj = 0; jj < 256; ++jj) acc += Up[jj << 8];
        part[(jg << 8) + k] = acc;
    }
    __syncthreads();
    if (tid < 256)
        t_lds[tid] = (part[tid] + part[256 + tid] + part[512 + tid] +
                      part[768 + tid]) * (1.0f / 1024.0f);
    __syncthreads();

    // s-phase + squash: wave = capsule (two halves: iG = wv, wv+16)
    {
        const int lane = tid & 63, wv = tid >> 6;
        #pragma unroll
        for (int half = 0; half < 2; ++half) {
            int iG = (half << 4) + wv;
            const float* Wc = W + (iG << 6) + lane;   // coalesced 256B per k
            float s = 0.f;
            #pragma unroll 4
            for (int k = 0; k < 256; ++k) s += t_lds[k] * Wc[k * 2048];
            float n2 = s * s;
            #pragma unroll
            for (int m = 1; m < 64; m <<= 1) n2 += __shfl_xor(n2, m, 64);
            float v = s * rsqrtf(n2 + 1e-7f);         // sef = 1 at iter 0
            v_all[(iG << 6) + lane] = v;
        }
    }
    __syncthreads();

    // w-phase (direct W, no WT): thread = (iG = tid>>5, k8 = tid&31),
    // 8 k's per thread; each output reads a contiguous 256B W row chunk.
    {
        int iG = tid >> 5, k8 = tid & 31;
        int g2 = iG >> 4, il = iG & 15;
        int bg = (b << 1) | g2;
        const float* vv = &v_all[iG << 6];
        const float4* W4 = (const float4*)W;          // 512 float4 per row
        float wk[8];
        #pragma unroll
        for (int e = 0; e < 8; ++e) {
            int k = (k8 << 3) + e;
            const float4* Wr = W4 + k * 512 + (iG << 4);
            float acc = 0.f;
            #pragma unroll
            for (int dq = 0; dq < 16; ++dq) {
                float4 wq = Wr[dq];
                acc += vv[(dq << 2) + 0] * wq.x + vv[(dq << 2) + 1] * wq.y +
                       vv[(dq << 2) + 2] * wq.z + vv[(dq << 2) + 3] * wq.w;
            }
            wk[e] = acc;
        }
        short h8[8], l8[8];
        #pragma unroll
        for (int e = 0; e < 8; ++e) {
            unsigned short h = f2bf(wk[e]);
            h8[e] = (short)h;
            l8[e] = (short)f2bf(wk[e] - bf2f(h));
        }
        int base = (((bg << 4) + il) << 8) + (k8 << 3);
        *(v8s*)&wbt_h[base] = (v8s){h8[0], h8[1], h8[2], h8[3],
                                    h8[4], h8[5], h8[6], h8[7]};
        *(v8s*)&wbt_l[base] = (v8s){l8[0], l8[1], l8[2], l8[3],
                                    l8[4], l8[5], l8[6], l8[7]};
    }
}

// ---------------------------------------------------------------------------
// k_sv (R0-proven body, mode-1 only): per (b,iG): t[k] = sum of 16 partials;
// s = tW_i; v = squash(.,sef); w = W_i v -> wbt hi/lo. grid 1024, block 256.
__global__ __launch_bounds__(256) void k_sv(const float* __restrict__ tpart,
                                            const float* __restrict__ sefpart,
                                            const float* __restrict__ W,
                                            const float* __restrict__ WT,
                                            short* __restrict__ wbt_h,
                                            short* __restrict__ wbt_l,
                                            float* __restrict__ out,
                                            int writeOut) {
    __shared__ float t_lds[256];
    __shared__ float spart[256];
    __shared__ __align__(16) float v_lds[64];
    __shared__ __align__(16) v4f spartw[256];
    __shared__ float sefv_s;
    int bid = blockIdx.x, tid = threadIdx.x;
    int b = bid >> 5, iG = bid & 31;
    int bg = (b << 1) | (iG >> 4), il = iG & 15;

    float acc = 0.f;
    {
        const float* tb = tpart + (((bg << 4) + il) << 8) + tid;
        #pragma unroll
        for (int p = 0; p < 16; ++p) acc += tb[p << 18];  // stride 64*16*256
        if (tid == 0) {
            float s = 0.f;
            #pragma unroll
            for (int p = 0; p < 16; ++p) s += sefpart[(p << 10) + (bg << 4) + il];
            sefv_s = s;
        }
    }
    t_lds[tid] = acc;
    __syncthreads();

    // s-phase: (d = tid&63, kq = tid>>6), coalesced 256B W reads
    int d = tid & 63, kq = tid >> 6;
    const float* Wc = W + ((kq << 6) * 2048) + (iG << 6) + d;
    float s = 0.f;
    #pragma unroll 4
    for (int kk = 0; kk < 64; ++kk)
        s += t_lds[(kq << 6) + kk] * Wc[kk * 2048];
    spart[tid] = s;
    __syncthreads();

    if (tid < 64) {
        float sv = spart[tid] + spart[tid + 64] + spart[tid + 128] + spart[tid + 192];
        float n2 = sv * sv;
        #pragma unroll
        for (int m = 1; m < 64; m <<= 1) n2 += __shfl_xor(n2, m, 64);
        float sf = sefv_s;
        float v = sv * rsqrtf(n2 + 1e-7f * sf * sf);
        v_lds[tid] = v;
        if (writeOut) out[(bid << 6) + tid] = v;
    }
    __syncthreads();
    if (writeOut) return;

    // w-phase: (k4 = tid&63, dq = tid>>6), WT gives coalesced 1KB/instr reads
    int k4 = tid & 63, dq = tid >> 6;
    const float4* WT4 = (const float4*)WT;
    v4f wp = {0.f, 0.f, 0.f, 0.f};
    #pragma unroll
    for (int dd = 0; dd < 16; ++dd) {
        float vv = v_lds[(dq << 4) + dd];
        float4 wt = WT4[((iG << 6) + (dq << 4) + dd) * 64 + k4];
        wp.x += vv * wt.x; wp.y += vv * wt.y; wp.z += vv * wt.z; wp.w += vv * wt.w;
    }
    spartw[(dq << 6) + k4] = wp;
    __syncthreads();
    if (tid < 64) {
        v4f w = spartw[tid] + spartw[64 + tid] + spartw[128 + tid] + spartw[192 + tid];
        float wv4[4] = {w.x, w.y, w.z, w.w};
        unsigned short wh[4], wl[4];
        #pragma unroll
        for (int e = 0; e < 4; ++e) {
            wh[e] = f2bf(wv4[e]);
            wl[e] = f2bf(wv4[e] - bf2f(wh[e]));
        }
        int base = (((bg << 4) + il) << 8) + (tid << 2);
        *(v4s*)&wbt_h[base] = (v4s){(short)wh[0], (short)wh[1], (short)wh[2], (short)wh[3]};
        *(v4s*)&wbt_l[base] = (v4s){(short)wl[0], (short)wl[1], (short)wl[2], (short)wl[3]};
    }
}

// ---------------------------------------------------------------------------
// k_pass (R16-proven): grid 512 (b = blk&31, p = blk>>5), block 1024 = 16
// waves, 2 barriers. D: waves 0-7 full-K=256 register chain, logits+exp on
// the accumulator; T: 16 waves, 2 k-tiles each.
__global__ __launch_bounds__(1024, 8) void k_pass(const float* __restrict__ U,
                                                  const short* __restrict__ wbt_h,
                                                  const short* __restrict__ wbt_l,
                                                  float* __restrict__ bmatg,
                                                  float* __restrict__ tpart_out,
                                                  float* __restrict__ sefpart_out,
                                                  int addold) {
    __shared__ short s_U[64 * 268];        // 34,304 B [j][k] pad 12
    __shared__ short s_wh[2 * 16 * 264];   // 16,896 [g2][i][k] pad 8
    __shared__ short s_wl[2 * 16 * 264];   // 16,896
    __shared__ short s_eh[2 * 16 * 72];    // 4,608  [g2][i][j] pad 8
    __shared__ short s_el[2 * 16 * 72];    // 4,608
    __shared__ float s_sefp[8 * 16];       // 512  tot 77,824

    const int tid = threadIdx.x, wv = tid >> 6, lane = tid & 63;
    const int quad = lane >> 4, nn = lane & 15;
    const int blk = blockIdx.x;
    const int b = blk & 31, p = blk >> 5;
    const int rowbase = (b << 10) + (p << 6);

    // ---- stage U (f32 -> bf16) and w (both g2) ----
    {
        const float4* U4 = (const float4*)U;
        int col = tid & 63, row0 = tid >> 6;
        float4 g[4];
        #pragma unroll
        for (int q = 0; q < 4; ++q)
            g[q] = U4[(rowbase + row0 + (q << 4)) * 64 + col];
        #pragma unroll
        for (int q = 0; q < 4; ++q)
            *(v4s*)&s_U[(row0 + (q << 4)) * 268 + (col << 2)] =
                (v4s){(short)f2bf(g[q].x), (short)f2bf(g[q].y),
                      (short)f2bf(g[q].z), (short)f2bf(g[q].w)};
        int row = tid >> 5, seg = tid & 31;
        int gidx = (((b << 5) + row) << 8) + (seg << 3);
        int lidx = (row >> 4) * 4224 + (row & 15) * 264 + (seg << 3);
        *(v8s*)&s_wh[lidx] = *(const v8s*)(wbt_h + gidx);
        *(v8s*)&s_wl[lidx] = *(const v8s*)(wbt_l + gidx);
    }
    __syncthreads();

    // ---- phase D: waves 0-7 = (jt = wv&3, g2 = wv>>2), full K=256 ----
    if (wv < 8) {
        const int jt = wv & 3, g2 = wv >> 2;
        const int bg = (b << 1) | g2;
        v4f dacc = {0.f, 0.f, 0.f, 0.f};
        #pragma unroll
        for (int c = 0; c < 8; ++c) {
            int kb = (c << 5) + (quad << 3);
            v8s a  = *(const v8s*)&s_U[((jt << 4) + nn) * 268 + kb];
            v8s bh = *(const v8s*)&s_wh[g2 * 4224 + nn * 264 + kb];
            v8s bl = *(const v8s*)&s_wl[g2 * 4224 + nn * 264 + kb];
            dacc = __builtin_amdgcn_mfma_f32_16x16x32_bf16(a, bh, dacc, 0, 0, 0);
            dacc = __builtin_amdgcn_mfma_f32_16x16x32_bf16(a, bl, dacc, 0, 0, 0);
        }
        float se = 0.f;
        #pragma unroll
        for (int r = 0; r < 4; ++r) {
            int jloc = (jt << 4) + (quad << 2) + r;
            int ga = (((bg << 10) + (p << 6) + jloc) << 4) + nn;
            float val = dacc[r];
            if (addold) val += bmatg[ga];
            else bmatg[ga] = val;
            float e = __expf(val);
            unsigned short eh = f2bf(e);
            s_eh[g2 * 1152 + nn * 72 + jloc] = (short)eh;
            s_el[g2 * 1152 + nn * 72 + jloc] = (short)f2bf(e - bf2f(eh));
            se += e;
        }
        se += __shfl_xor(se, 16, 64);
        se += __shfl_xor(se, 32, 64);
        if (lane < 16) s_sefp[((g2 << 2) + jt) << 4 | lane] = se;
    }
    __syncthreads();

    // ---- phase T: 16 waves = (g2 = wv>>3, kt2 = wv&7), 2 k-tiles each ----
    {
        const int g2 = wv >> 3, kt2 = wv & 7;
        const int bg = (b << 1) | g2;
        #pragma unroll
        for (int task = 0; task < 2; ++task) {
            const int k0 = ((task << 3) + kt2) << 4;
            v4f tacc = {0.f, 0.f, 0.f, 0.f};
            #pragma unroll
            for (int jc = 0; jc < 2; ++jc) {
                v8s aeh = *(const v8s*)&s_eh[g2 * 1152 + nn * 72 + (jc << 5) + (quad << 3)];
                v8s ael = *(const v8s*)&s_el[g2 * 1152 + nn * 72 + (jc << 5) + (quad << 3)];
                short bu[8];
                #pragma unroll
                for (int jj = 0; jj < 8; ++jj)
                    bu[jj] = s_U[((jc << 5) + (quad << 3) + jj) * 268 + k0 + nn];
                v8s bf = (v8s){bu[0], bu[1], bu[2], bu[3],
                               bu[4], bu[5], bu[6], bu[7]};
                tacc = __builtin_amdgcn_mfma_f32_16x16x32_bf16(aeh, bf, tacc, 0, 0, 0);
                tacc = __builtin_amdgcn_mfma_f32_16x16x32_bf16(ael, bf, tacc, 0, 0, 0);
            }
            #pragma unroll
            for (int r = 0; r < 4; ++r) {
                int i = (quad << 2) + r;
                tpart_out[(((((p << 6) + bg) << 4) + i) << 8) + k0 + nn] = tacc[r];
            }
        }
    }
    if (tid < 32) {
        int g2 = tid >> 4, i = tid & 15;
        float ss = 0.f;
        #pragma unroll
        for (int jt = 0; jt < 4; ++jt) ss += s_sefp[((g2 << 2) + jt) << 4 | i];
        sefpart_out[(p << 10) + (((b << 1) | g2) << 4) + i] = ss;
    }
}

// ---------------------------------------------------------------------------
extern "C" void kernel_launch(void* const* d_in, const int* in_sizes, int n_in,
                              void* d_out, int out_size, void* d_ws, size_t ws_size,
                              hipStream_t stream) {
    const float* U = (const float*)d_in[0];   // [32,1024,256]
    const float* W = (const float*)d_in[1];   // [256,2048]
    float* out = (float*)d_out;               // [32,32,64]
    float* ws = (float*)d_ws;

    float* WT    = ws;                  // [2048][256]        = 524,288
    float* bmatg = WT + 524288;         // [64][1024][16]     = 1,048,576
    float* tp    = bmatg + 1048576;     // [16][64][16][256]  = 4,194,304
    float* sefp  = tp + 4194304;        // [16][64][16]       = 16,384
    short* wbt_h = (short*)(sefp + 16384);  // [64][16][256] shorts
    short* wbt_l = wbt_h + 262144;

    k_sv0d<<<160, 1024, 0, stream>>>(U, W, WT, wbt_h, wbt_l);
    k_pass<<<512, 1024, 0, stream>>>(U, wbt_h, wbt_l, bmatg, tp, sefp, 0);
    k_sv<<<1024, 256, 0, stream>>>(tp, sefp, W, WT, wbt_h, wbt_l, out, 0);
    k_pass<<<512, 1024, 0, stream>>>(U, wbt_h, wbt_l, bmatg, tp, sefp, 1);
    k_sv<<<1024, 256, 0, stream>>>(tp, sefp, W, WT, wbt_h, wbt_l, out, 1);
}